// Round 4
// baseline (545.933 us; speedup 1.0000x reference)
//
#include <hip/hip_runtime.h>

typedef float f32x2 __attribute__((ext_vector_type(2)));

// NOTE: h is stored as fp8 e4m3 (HW cvt, RNE) -- 3.2 MB, per-XCD L2-resident.
// NOTE: CSR built via global-atomic 3-pass: deg/wsum atomics -> single-block
//       scan (rowptr, lofs, dis) -> scatter with dis[src] folded into weight.
//       Edge order within a row is atomic-arrival order (fp sum reorder is
//       within the fp8-dominated tolerance, same as the old LDS-atomic order).

#define NBD 512   // deg-accumulation blocks inside k_front
#define NBS 1024  // scatter blocks

// ---------- helpers ----------
__device__ __forceinline__ long ld_idx(const void* idx, long pos, int is64) {
  return is64 ? (long)((const long long*)idx)[pos]
              : (long)((const int*)idx)[pos];
}

// Per-wave dtype detection: true int64 indices are all < 2^32.
__device__ __forceinline__ int detect_is64(const void* idx) {
  const unsigned long long* p = (const unsigned long long*)idx;
  unsigned long long v = p[threadIdx.x & 63];
  return (__ballot((v >> 32) != 0ull) == 0ull) ? 1 : 0;
}

// ---------- fp8 pack helper: 16 fp32 -> 16 e4m3 bytes (uint4) ----------
__device__ __forceinline__ uint4 pack16_fp8(const float* acc) {
  uint4 o;
  unsigned v;
  v = 0;
  v = __builtin_amdgcn_cvt_pk_fp8_f32(acc[0],  acc[1],  v, false);
  v = __builtin_amdgcn_cvt_pk_fp8_f32(acc[2],  acc[3],  v, true);
  o.x = v; v = 0;
  v = __builtin_amdgcn_cvt_pk_fp8_f32(acc[4],  acc[5],  v, false);
  v = __builtin_amdgcn_cvt_pk_fp8_f32(acc[6],  acc[7],  v, true);
  o.y = v; v = 0;
  v = __builtin_amdgcn_cvt_pk_fp8_f32(acc[8],  acc[9],  v, false);
  v = __builtin_amdgcn_cvt_pk_fp8_f32(acc[10], acc[11], v, true);
  o.z = v; v = 0;
  v = __builtin_amdgcn_cvt_pk_fp8_f32(acc[12], acc[13], v, false);
  v = __builtin_amdgcn_cvt_pk_fp8_f32(acc[14], acc[15], v, true);
  o.w = v;
  return o;
}

// ---------- FRONT: blocks [0,NBD) = deg/wsum global atomics;
//                   blocks [NBD,..) = gemm1 (4 threads/node, W1 in LDS) ----------
__global__ __launch_bounds__(256) void k_front(const void* __restrict__ idx,
                                               const float* __restrict__ w,
                                               uint2* __restrict__ degw, long E,
                                               const float* __restrict__ X,
                                               const float* __restrict__ W1,
                                               unsigned char* __restrict__ h, int n) {
  __shared__ float smem[2048];   // gemm1 W tile (8 KB); deg blocks don't use it
  const int t = threadIdx.x;
  if (blockIdx.x < NBD) {
    const int is64 = detect_is64(idx);
    long i0 = (long)blockIdx.x * 256 + t;
    long stride = (long)NBD * 256;
    for (long e = i0; e < E; e += stride) {
      unsigned d = (unsigned)ld_idx(idx, E + e, is64);
      float wv = w[e];
      atomicAdd(&degw[d].x, 1u);
      atomicAdd((float*)&degw[d].y, wv);
    }
    return;
  }
  // ----- gemm1 -----
  float* Ws = smem;
  for (int i = t; i < 2048; i += 256)
    ((float4*)Ws)[i] = ((const float4*)W1)[i];
  __syncthreads();
  int gid = (blockIdx.x - NBD) * 256 + t;
  int node = gid >> 2;
  int fg = (gid & 3) * 16;
  if (node >= n) return;
  const float4* xr4 = (const float4*)(X + (size_t)node * 128);
  float acc[16];
#pragma unroll
  for (int f = 0; f < 16; ++f) acc[f] = 0.0f;
  for (int k4 = 0; k4 < 32; ++k4) {
    float4 x = xr4[k4];
#pragma unroll
    for (int kk = 0; kk < 4; ++kk) {
      float xv = (kk == 0) ? x.x : (kk == 1) ? x.y : (kk == 2) ? x.z : x.w;
      const float4* wrow = (const float4*)(Ws + (k4 * 4 + kk) * 64 + fg);
#pragma unroll
      for (int f4 = 0; f4 < 4; ++f4) {
        float4 w4 = wrow[f4];
        acc[f4 * 4 + 0] = fmaf(xv, w4.x, acc[f4 * 4 + 0]);
        acc[f4 * 4 + 1] = fmaf(xv, w4.y, acc[f4 * 4 + 1]);
        acc[f4 * 4 + 2] = fmaf(xv, w4.z, acc[f4 * 4 + 2]);
        acc[f4 * 4 + 3] = fmaf(xv, w4.w, acc[f4 * 4 + 3]);
      }
    }
  }
  *(uint4*)(h + (size_t)node * 64 + fg) = pack16_fp8(acc);
}

// ---------- SCAN: single block; rowptr/lofs prefix over deg, dis from wsum ----------
__global__ __launch_bounds__(1024) void k_scan(const uint2* __restrict__ degw,
                                               int* __restrict__ rowptr,
                                               unsigned* __restrict__ lofs,
                                               float* __restrict__ dis, int n, long E) {
  __shared__ unsigned sh[1024];
  const int t = threadIdx.x;
  const int per = (n + 1023) >> 10;
  const int i0 = t * per;
  const int i1 = min(i0 + per, n);
  unsigned s = 0;
  for (int i = i0; i < i1; ++i) s += degw[i].x;
  sh[t] = s;
  __syncthreads();
  for (int off = 1; off < 1024; off <<= 1) {
    unsigned u = (t >= off) ? sh[t - off] : 0;
    __syncthreads();
    sh[t] += u;
    __syncthreads();
  }
  unsigned run = sh[t] - s;   // exclusive prefix of this thread's segment
  for (int i = i0; i < i1; ++i) {
    uint2 dw = degw[i];
    rowptr[i] = (int)run;
    lofs[i] = run;
    dis[i] = rsqrtf(1.0f + __uint_as_float(dw.y));  // deg >= 1 (self-loop wt 1)
    run += dw.x;
  }
  if (t == 0) rowptr[n] = (int)E;
}

// ---------- SCATTER: CSR placement, dis[src] folded into stored weight ----------
__global__ __launch_bounds__(256) void k_scatter(const void* __restrict__ idx,
                                                 const float* __restrict__ w,
                                                 const float* __restrict__ dis,
                                                 unsigned* __restrict__ lofs,
                                                 float2* __restrict__ edges, long E) {
  const int is64 = detect_is64(idx);
  long i0 = (long)blockIdx.x * 256 + threadIdx.x;
  long stride = (long)gridDim.x * 256;
  for (long e = i0; e < E; e += stride) {
    unsigned s = (unsigned)ld_idx(idx, e, is64);
    unsigned d = (unsigned)ld_idx(idx, E + e, is64);
    float wn = w[e] * dis[s];
    unsigned pos = atomicAdd(&lofs[d], 1u);
    edges[pos] = make_float2(__uint_as_float(s), wn);
  }
}

// ---------- gather core: aggregate one node's neighborhood (2 nodes/wave) ----------
// Latency-flattened: a single 12-slot window (48 edges; covers deg for ~99.8%
// of nodes) issues ALL rec loads, then ALL h-row loads, then the FMA block.
// 8 feature-lanes share each rec address (HW broadcast); tail slots clamp to
// end-1 and zero the weight. Weight already carries dis[src] (k_scatter).
__device__ __forceinline__ void gather_acc(const unsigned char* __restrict__ h,
                                           const float2* __restrict__ edges,
                                           int beg, int end, int eg, int fl,
                                           float* acc) {
  f32x2 a0 = {0.0f, 0.0f}, a1 = {0.0f, 0.0f}, a2 = {0.0f, 0.0f}, a3 = {0.0f, 0.0f};
  const unsigned char* hf = h + fl * 8;
  for (int base = beg; base < end; base += 48) {
    float2 rv[12];
#pragma unroll
    for (int s = 0; s < 12; ++s) {
      int idx = base + s * 4 + eg;
      rv[s] = edges[min(idx, end - 1)];
    }
    uint2 hv[12];
#pragma unroll
    for (int s = 0; s < 12; ++s)
      hv[s] = *(const uint2*)(hf + (size_t)__float_as_int(rv[s].x) * 64);
#pragma unroll
    for (int s = 0; s < 12; ++s) {
      float w = (base + s * 4 + eg < end) ? rv[s].y : 0.0f;
      f32x2 nj2 = {w, w};
      a0 += __builtin_amdgcn_cvt_pk_f32_fp8(hv[s].x, false) * nj2;
      a1 += __builtin_amdgcn_cvt_pk_f32_fp8(hv[s].x, true)  * nj2;
      a2 += __builtin_amdgcn_cvt_pk_f32_fp8(hv[s].y, false) * nj2;
      a3 += __builtin_amdgcn_cvt_pk_f32_fp8(hv[s].y, true)  * nj2;
    }
  }
  acc[0] = a0[0]; acc[1] = a0[1]; acc[2] = a1[0]; acc[3] = a1[1];
  acc[4] = a2[0]; acc[5] = a2[1]; acc[6] = a3[0]; acc[7] = a3[1];
#pragma unroll
  for (int off = 8; off < 32; off <<= 1)
#pragma unroll
    for (int i = 0; i < 8; ++i) acc[i] += __shfl_xor(acc[i], off);
}

// epilogue helper: acc += b + h_self * s0^2
__device__ __forceinline__ void add_bias_self(const unsigned char* __restrict__ h,
                                              const float* __restrict__ b,
                                              int node, int fl, float s0, float* acc) {
  uint2 hv = *(const uint2*)(h + (size_t)node * 64 + fl * 8);
  f32x2 q0 = __builtin_amdgcn_cvt_pk_f32_fp8(hv.x, false);
  f32x2 q1 = __builtin_amdgcn_cvt_pk_f32_fp8(hv.x, true);
  f32x2 q2 = __builtin_amdgcn_cvt_pk_f32_fp8(hv.y, false);
  f32x2 q3 = __builtin_amdgcn_cvt_pk_f32_fp8(hv.y, true);
  float hs[8] = {q0[0], q0[1], q1[0], q1[1], q2[0], q2[1], q3[0], q3[1]};
  float4 bv0 = *(const float4*)(b + fl * 8);
  float4 bv1 = *(const float4*)(b + fl * 8 + 4);
  float bb[8] = {bv0.x, bv0.y, bv0.z, bv0.w, bv1.x, bv1.y, bv1.z, bv1.w};
  float s2 = s0 * s0;
#pragma unroll
  for (int i = 0; i < 8; ++i) acc[i] += bb[i] + hs[i] * s2;
}

// ---------- MID: gather layer-1 + fused gemm2 -> layer-2 h (fp8) ----------
__global__ __launch_bounds__(256) void k_gather_mid(const unsigned char* __restrict__ h,
                                                    const float* __restrict__ dis,
                                                    const float2* __restrict__ edges,
                                                    const int* __restrict__ rowptr,
                                                    const float* __restrict__ b1,
                                                    const float* __restrict__ W2,
                                                    unsigned char* __restrict__ h2, int n) {
  __shared__ float W2s[64 * 64];   // 16 KB
  __shared__ float xs[8 * 64];     // 2 KB: relu'd layer-1 output for this block's 8 nodes
  const int t = threadIdx.x;
  for (int i = t; i < 1024; i += 256)
    ((float4*)W2s)[i] = ((const float4*)W2)[i];
  int lane = t & 63;
  int l32 = lane & 31;
  int fl = lane & 7;
  int eg = (lane >> 3) & 3;
  int nl = t >> 5;                       // node-local 0..7
  int node = blockIdx.x * 8 + nl;
  int beg = 0, end = 0; float s0 = 0.0f;
  if (node < n) { beg = rowptr[node]; end = rowptr[node + 1]; s0 = dis[node]; }
  float acc[8];
  gather_acc(h, edges, beg, end, eg, fl, acc);
  if (node < n) {
#pragma unroll
    for (int i = 0; i < 8; ++i) acc[i] *= s0;
    add_bias_self(h, b1, node, fl, s0, acc);
    if (eg == 0) {
#pragma unroll
      for (int i = 0; i < 8; ++i) xs[nl * 64 + fl * 8 + i] = fmaxf(acc[i], 0.0f);
    }
  }
  __syncthreads();
  // gemm2: thread t computes outputs f=2*tl, 2*tl+1 for node-local nl
  int tl = l32;  // t>>5 == nl, t&31 within node
  int node2 = blockIdx.x * 8 + (t >> 5);
  if (node2 >= n) return;
  const float* xrow = xs + (t >> 5) * 64;
  int f = tl * 2;
  float a0 = 0.0f, a1 = 0.0f;
#pragma unroll 8
  for (int k = 0; k < 64; ++k) {
    float xk = xrow[k];
    f32x2 wv = *(const f32x2*)(W2s + k * 64 + f);
    a0 = fmaf(xk, wv[0], a0);
    a1 = fmaf(xk, wv[1], a1);
  }
  unsigned v = __builtin_amdgcn_cvt_pk_fp8_f32(a0, a1, 0u, false);
  *(unsigned short*)(h2 + (size_t)node2 * 64 + f) = (unsigned short)v;
}

// ---------- FIN: gather layer-2 + readout (sigmoid(relu(z) . Wl + bl)) ----------
__global__ __launch_bounds__(256) void k_gather_fin(const unsigned char* __restrict__ h,
                                                    const float* __restrict__ dis,
                                                    const float2* __restrict__ edges,
                                                    const int* __restrict__ rowptr,
                                                    const float* __restrict__ b2,
                                                    const float* __restrict__ Wl,
                                                    const float* __restrict__ bl,
                                                    float* __restrict__ out, int n) {
  int lane = threadIdx.x & 63;
  int l32 = lane & 31;
  int fl = lane & 7;
  int eg = (lane >> 3) & 3;
  int node = blockIdx.x * 8 + (int)(threadIdx.x >> 5);
  if (node >= n) return;
  int beg = rowptr[node], end = rowptr[node + 1];
  float s0 = dis[node];
  float acc[8];
  gather_acc(h, edges, beg, end, eg, fl, acc);
#pragma unroll
  for (int i = 0; i < 8; ++i) acc[i] *= s0;
  add_bias_self(h, b2, node, fl, s0, acc);
  float4 wl0 = *(const float4*)(Wl + fl * 8);
  float4 wl1 = *(const float4*)(Wl + fl * 8 + 4);
  float wl[8] = {wl0.x, wl0.y, wl0.z, wl0.w, wl1.x, wl1.y, wl1.z, wl1.w};
  float v = 0.0f;
#pragma unroll
  for (int i = 0; i < 8; ++i) v += fmaxf(acc[i], 0.0f) * wl[i];
#pragma unroll
  for (int off = 1; off < 8; off <<= 1) v += __shfl_xor(v, off);
  if (l32 == 0) out[node] = 1.0f / (1.0f + expf(-(v + bl[0])));
}

extern "C" void kernel_launch(void* const* d_in, const int* in_sizes, int n_in,
                              void* d_out, int out_size, void* d_ws, size_t ws_size,
                              hipStream_t stream) {
  const float* X  = (const float*)d_in[0];
  const void*  EI = d_in[1];
  const float* EW = (const float*)d_in[2];
  const float* W1 = (const float*)d_in[3];
  const float* b1 = (const float*)d_in[4];
  const float* W2 = (const float*)d_in[5];
  const float* b2 = (const float*)d_in[6];
  const float* Wl = (const float*)d_in[7];
  const float* bl = (const float*)d_in[8];
  float* out = (float*)d_out;

  const int  n = in_sizes[0] / 128;      // 50000
  const long E = (long)in_sizes[1] / 2;  // 1,600,000

  auto align = [](size_t x) { return (x + 255) & ~(size_t)255; };
  char* ws = (char*)d_ws;
  size_t off = 0;
  float*         dis    = (float*)(ws + off);         off += align((size_t)n * 4);
  int*           rowptr = (int*)(ws + off);           off += align((size_t)(n + 1) * 4);
  uint2*         degw   = (uint2*)(ws + off);         off += align((size_t)n * 8);
  unsigned*      lofs   = (unsigned*)(ws + off);      off += align((size_t)n * 4);
  float2*        edges  = (float2*)(ws + off);        off += align((size_t)E * 8);
  unsigned char* A      = (unsigned char*)(ws + off); off += align((size_t)n * 64);
  unsigned char* A2     = (unsigned char*)(ws + off); off += align((size_t)n * 64);

  const int nbW = (n + 7) / 8;          // 8 nodes/block gathers
  const int nbG = (n * 4 + 255) / 256;  // gemm1 blocks (4 threads/node)

  // zero deg/wsum (workspace arrives poisoned)
  hipMemsetAsync(degw, 0, (size_t)n * 8, stream);

  // deg/wsum atomics (blocks [0,NBD)) + gemm1 (blocks [NBD,..)) in one launch
  k_front<<<NBD + nbG, dim3(256), 0, stream>>>(EI, EW, degw, E, X, W1, A, n);
  // rowptr / lofs / dis
  k_scan<<<1, dim3(1024), 0, stream>>>(degw, rowptr, lofs, dis, n, E);
  // CSR scatter with dis[src] folded into weight
  k_scatter<<<NBS, dim3(256), 0, stream>>>(EI, EW, dis, lofs, edges, E);

  // layer 1 gather + fused layer-2 GEMM
  k_gather_mid<<<nbW, dim3(256), 0, stream>>>(A, dis, edges, rowptr, b1, W2, A2, n);
  // layer 2 gather + fused readout
  k_gather_fin<<<nbW, dim3(256), 0, stream>>>(A2, dis, edges, rowptr, b2, Wl, bl, out, n);
}